// Round 16
// baseline (443.173 us; speedup 1.0000x reference)
//
#include <hip/hip_runtime.h>
#include <hip/hip_bf16.h>

#define T_TOK 2048
#define H_DIM 2048
#define E_NUM 32
#define I_DIM 768
#define TOPK  4
#define S4    (T_TOK * TOPK)          // 8192 slots

typedef __attribute__((ext_vector_type(8))) short bf16x8;
typedef __attribute__((ext_vector_type(4))) float f32x4;

__device__ __forceinline__ unsigned pk2(float a, float b) {
    __hip_bfloat16 ha = __float2bfloat16(a);
    __hip_bfloat16 hb = __float2bfloat16(b);
    unsigned short ua = *(unsigned short*)&ha;
    unsigned short ub = *(unsigned short*)&hb;
    return (unsigned)ua | ((unsigned)ub << 16);
}

#define MFMA16(a, b, c) __builtin_amdgcn_mfma_f32_16x16x32_bf16(a, b, c, 0, 0, 0)

// ---------------- Router ----------------
__global__ __launch_bounds__(64) void router_kernel(
    const float* __restrict__ x, const float* __restrict__ gate_w,
    float* __restrict__ logits_out, int* __restrict__ cnt,
    int* __restrict__ tok_list, float* __restrict__ tok_w,
    int* __restrict__ tok_slots)
{
    const int t = blockIdx.x;
    const int lane = threadIdx.x;
    __shared__ float xs[H_DIM];
    const float4* __restrict__ xv = (const float4*)(x + (size_t)t * H_DIM);
    float4* xsv = (float4*)xs;
#pragma unroll
    for (int i = 0; i < H_DIM / 4 / 64; ++i) xsv[lane + i * 64] = xv[lane + i * 64];
    __syncthreads();

    const int e = lane & 31;
    const int half = lane >> 5;
    const float4* __restrict__ wv = (const float4*)(gate_w + (size_t)e * H_DIM) + half * (H_DIM / 8);
    const float4* __restrict__ xh = ((const float4*)xs) + half * (H_DIM / 8);
    float acc = 0.f;
#pragma unroll 4
    for (int i = 0; i < H_DIM / 8; ++i) {
        float4 w4 = wv[i], x4 = xh[i];
        acc += w4.x * x4.x + w4.y * x4.y + w4.z * x4.z + w4.w * x4.w;
    }
    acc += __shfl_xor(acc, 32, 64);
    if (lane < 32) logits_out[(size_t)t * E_NUM + e] = acc;

    float v = acc;
    float topv[TOPK]; int topi[TOPK];
#pragma unroll
    for (int r = 0; r < TOPK; ++r) {
        float bv = v; int bi = e;
#pragma unroll
        for (int off = 16; off >= 1; off >>= 1) {
            float ov = __shfl_xor(bv, off, 32);
            int   oi = __shfl_xor(bi, off, 32);
            if (ov > bv || (ov == bv && oi < bi)) { bv = ov; bi = oi; }
        }
        topv[r] = bv; topi[r] = bi;
        if (e == bi) v = -1e30f;
    }
    if (lane == 0) {
        float w[TOPK]; float s = 0.f;
#pragma unroll
        for (int r = 0; r < TOPK; ++r) { w[r] = expf(topv[r] - topv[0]); s += w[r]; }
        float inv = 1.f / s;
#pragma unroll
        for (int r = 0; r < TOPK; ++r) {
            int pos = atomicAdd(&cnt[topi[r]], 1);
            tok_list[topi[r] * T_TOK + pos] = t;
            tok_w  [topi[r] * T_TOK + pos] = w[r] * inv;
            tok_slots[t * TOPK + r] = (topi[r] << 12) | pos;
        }
    }
}

__global__ void scan_kernel(const int* __restrict__ cnt, int* __restrict__ slot_base)
{
    if (threadIdx.x == 0) {
        int s = 0;
        for (int e = 0; e < E_NUM; ++e) { slot_base[e] = s; s += cnt[e]; }
        slot_base[E_NUM] = s;
    }
}

// ------- Gather tokens per expert, convert x -> bf16 in K-PANEL layout -------
__global__ __launch_bounds__(256) void gather_kernel(
    const float* __restrict__ x, const int* __restrict__ cnt,
    const int* __restrict__ slot_base, const int* __restrict__ tok_list,
    unsigned short* __restrict__ xg_t)
{
    const int e = blockIdx.x;
    const int count = cnt[e];
    const int m0 = blockIdx.y * 8;
    if (m0 >= count) return;
    const int s8   = threadIdx.x >> 5;
    const int kc31 = threadIdx.x & 31;
    const int m = m0 + s8;
    if (m >= count) return;
    const int tok  = tok_list[e * T_TOK + m];
    const int slot = slot_base[e] + m;
    const float* __restrict__ src = x + (size_t)tok * H_DIM;
#pragma unroll
    for (int kcq = 0; kcq < 8; ++kcq) {
        const int kc = kcq * 32 + kc31;
        float4 a = *(const float4*)(src + kc * 8);
        float4 b = *(const float4*)(src + kc * 8 + 4);
        uint4 o;
        o.x = pk2(a.x, a.y); o.y = pk2(a.z, a.w);
        o.z = pk2(b.x, b.y); o.w = pk2(b.z, b.w);
        *(uint4*)(xg_t + ((size_t)kc * S4 + slot) * 8) = o;
    }
}

// ---------------- gate_up MFMA + silu + weight-scale -> h_t (panel bf16) -----
// tile 256(M) x 32(g)+32(u); A in registers with interleaved depth-1 prefetch
// (next-chunk granule loads issue inside the s-loop, land under ~24 MFMAs);
// B per-128K chunk in LDS. grid (32e, 24nt, 8mt).
#define GU_NC (H_DIM / 128)   // 16 chunks
__global__ __launch_bounds__(512, 2) void gateup_mfma(
    const unsigned short* __restrict__ xg_t, const float* __restrict__ gup_w,
    const int* __restrict__ cnt, const int* __restrict__ slot_base,
    const float* __restrict__ tok_w, unsigned short* __restrict__ h_t)
{
    const int e  = blockIdx.x;
    const int nt = blockIdx.y;
    const int mt = blockIdx.z;
    const int count = cnt[e];
    if (mt * 256 >= count) return;
    const int tid  = threadIdx.x;
    const int lane = tid & 63;
    const int w    = tid >> 6;
    const int base = slot_base[e];
    const int l16  = lane & 15, lg = lane >> 4;

    __shared__ unsigned short Bls[2][2][16 * 32 * 8];  // [buf][half][kc16][n32][8] 32KB
    __shared__ float wls[256];                         // 1KB

    if (tid < 256) {
        int m = mt * 256 + tid; if (m >= count) m = count - 1;
        wls[tid] = tok_w[e * T_TOK + m];
    }

    int m0 = mt * 256 + w * 32 + l16;      if (m0 >= count) m0 = count - 1;
    int m1 = mt * 256 + w * 32 + 16 + l16; if (m1 >= count) m1 = count - 1;
    const unsigned short* a0b = xg_t + (size_t)(base + m0) * 8;
    const unsigned short* a1b = xg_t + (size_t)(base + m1) * 8;

    const int bhalf = tid >> 8;
    const int sub   = (tid >> 7) & 1;
    const int t7    = tid & 127;
    const int kb    = (t7 >> 3) * 2;
    const int n4    = (t7 & 7) * 4;
    const int k8    = kb & 7;
    const int kbh   = kb >> 3;
    const float* __restrict__ bbase =
        gup_w + ((size_t)e * H_DIM + kb) * (2 * I_DIM) + (size_t)bhalf * I_DIM + nt * 32 + n4;

    float4 sv0[2], sv1[2];
    bf16x8 aR[8];   // A block for current chunk: [s]=row0, [4+s]=row1 (static idx)

#define GU_ALOAD(C) do { _Pragma("unroll") for (int s = 0; s < 4; ++s) { \
        const size_t ao_ = (size_t)((C) * 16 + s * 4 + lg) * (S4 * 8); \
        aR[s]     = *(const bf16x8*)(a0b + ao_); \
        aR[4 + s] = *(const bf16x8*)(a1b + ao_); } } while (0)
#define GU_LOAD(C) do { _Pragma("unroll") for (int q2 = 0; q2 < 2; ++q2) { \
        const int q = sub + q2 * 2; \
        const float* s_ = bbase + (size_t)((C) * 128 + q * 32) * (2 * I_DIM); \
        sv0[q2] = *(const float4*)s_; \
        sv1[q2] = *(const float4*)(s_ + 2 * I_DIM); } } while (0)
#define GU_WRITE(BUF) do { _Pragma("unroll") for (int q2 = 0; q2 < 2; ++q2) { \
        const int q = sub + q2 * 2; \
        unsigned short* bw_ = &Bls[BUF][bhalf][((q * 4 + kbh) * 32) * 8]; \
        float p0[4] = {sv0[q2].x, sv0[q2].y, sv0[q2].z, sv0[q2].w}; \
        float p1[4] = {sv1[q2].x, sv1[q2].y, sv1[q2].z, sv1[q2].w}; \
        _Pragma("unroll") for (int j = 0; j < 4; ++j) \
            *(unsigned*)&bw_[(n4 + j) * 8 + k8] = pk2(p0[j], p1[j]); } } while (0)

    f32x4 accg[2][2], accu[2][2];
#pragma unroll
    for (int i = 0; i < 2; ++i)
#pragma unroll
        for (int f = 0; f < 2; ++f) { accg[i][f] = {0.f,0.f,0.f,0.f}; accu[i][f] = {0.f,0.f,0.f,0.f}; }

    GU_LOAD(0);
    GU_WRITE(0);
    GU_ALOAD(0);      // chunk 0 A prefetch (lands under barrier + B issue)

    for (int c = 0; c < GU_NC; ++c) {
        const int buf = c & 1;
        const bool pf = (c + 1 < GU_NC);
        __syncthreads();                     // Bls[buf] published for chunk c
        if (pf) GU_LOAD(c + 1);              // B regs for next chunk (issue-early)
#pragma unroll
        for (int s = 0; s < 4; ++s) {
            bf16x8 a0 = aR[s];
            bf16x8 a1 = aR[4 + s];
            if (pf) {                        // interleaved depth-1 A prefetch
                const size_t ao_ = (size_t)((c + 1) * 16 + s * 4 + lg) * (S4 * 8);
                aR[s]     = *(const bf16x8*)(a0b + ao_);
                aR[4 + s] = *(const bf16x8*)(a1b + ao_);
            }
            const unsigned short* bg_ = &Bls[buf][0][((s * 4 + lg) * 32 + l16) * 8];
            const unsigned short* bu_ = &Bls[buf][1][((s * 4 + lg) * 32 + l16) * 8];
            bf16x8 g0 = *(const bf16x8*)(bg_);
            bf16x8 g1 = *(const bf16x8*)(bg_ + 128);
            bf16x8 u0 = *(const bf16x8*)(bu_);
            bf16x8 u1 = *(const bf16x8*)(bu_ + 128);
            accg[0][0] = MFMA16(a0, g0, accg[0][0]);
            accg[0][1] = MFMA16(a0, g1, accg[0][1]);
            accu[0][0] = MFMA16(a0, u0, accu[0][0]);
            accu[0][1] = MFMA16(a0, u1, accu[0][1]);
            accg[1][0] = MFMA16(a1, g0, accg[1][0]);
            accg[1][1] = MFMA16(a1, g1, accg[1][1]);
            accu[1][0] = MFMA16(a1, u0, accu[1][0]);
            accu[1][1] = MFMA16(a1, u1, accu[1][1]);
        }
        if (pf) GU_WRITE(buf ^ 1);           // write-late (loads landed under MFMAs)
    }
#undef GU_ALOAD
#undef GU_LOAD
#undef GU_WRITE

#pragma unroll
    for (int i = 0; i < 2; ++i) {
        const int mloc = w * 32 + i * 16 + lg * 4;
#pragma unroll
        for (int r = 0; r < 4; ++r) {
            const int mrow = mt * 256 + mloc + r;
            if (mrow < count) {
                const float wgt = wls[mloc + r];
                const size_t slot = (size_t)(base + mrow);
#pragma unroll
                for (int f = 0; f < 2; ++f) {
                    const int col = nt * 32 + f * 16 + l16;
                    float g = accg[i][f][r], u = accu[i][f][r];
                    float sv = g / (1.f + expf(-g));
                    __hip_bfloat16 hb = __float2bfloat16(wgt * u * sv);
                    h_t[((size_t)(col >> 3) * S4 + slot) * 8 + (col & 7)] = *(unsigned short*)&hb;
                }
            }
        }
    }
}

// ---------------- down MFMA -> slot-major f32 rows (no atomics) ----------------
#define DN_NC (I_DIM / 128)   // 6 chunks
__global__ __launch_bounds__(512, 2) void down_mfma(
    const unsigned short* __restrict__ h_t, const float* __restrict__ down_w,
    const int* __restrict__ cnt, const int* __restrict__ slot_base,
    float* __restrict__ ods)
{
    const int e  = blockIdx.x;
    const int nt = blockIdx.y;
    const int mt = blockIdx.z;
    const int count = cnt[e];
    if (mt * 256 >= count) return;
    const int tid  = threadIdx.x;
    const int lane = tid & 63;
    const int w    = tid >> 6;
    const int base = slot_base[e];
    const int l16  = lane & 15, lg = lane >> 4;

    __shared__ unsigned short Bls[2][16 * 64 * 8];   // [buf][kc16][n64][8] 32KB

    int m0 = mt * 256 + w * 32 + l16;      if (m0 >= count) m0 = count - 1;
    int m1 = mt * 256 + w * 32 + 16 + l16; if (m1 >= count) m1 = count - 1;
    const unsigned short* a0b = h_t + (size_t)(base + m0) * 8;
    const unsigned short* a1b = h_t + (size_t)(base + m1) * 8;

    const int sub = tid >> 8;
    const int t8  = tid & 255;
    const int kb  = (t8 >> 4) * 2;
    const int n4  = (t8 & 15) * 4;
    const int k8  = kb & 7;
    const int kbh = kb >> 3;
    const float* __restrict__ bbase =
        down_w + ((size_t)e * I_DIM + kb) * H_DIM + nt * 64 + n4;

    float4 sv0[2], sv1[2];
    bf16x8 aR[8];

#define DN_ALOAD(C) do { _Pragma("unroll") for (int s = 0; s < 4; ++s) { \
        const size_t ao_ = (size_t)((C) * 16 + s * 4 + lg) * (S4 * 8); \
        aR[s]     = *(const bf16x8*)(a0b + ao_); \
        aR[4 + s] = *(const bf16x8*)(a1b + ao_); } } while (0)
#define DN_LOAD(C) do { _Pragma("unroll") for (int q2 = 0; q2 < 2; ++q2) { \
        const int q = sub + q2 * 2; \
        const float* s_ = bbase + (size_t)((C) * 128 + q * 32) * H_DIM; \
        sv0[q2] = *(const float4*)s_; \
        sv1[q2] = *(const float4*)(s_ + H_DIM); } } while (0)
#define DN_WRITE(BUF) do { _Pragma("unroll") for (int q2 = 0; q2 < 2; ++q2) { \
        const int q = sub + q2 * 2; \
        unsigned short* bw_ = &Bls[BUF][((q * 4 + kbh) * 64) * 8]; \
        float p0[4] = {sv0[q2].x, sv0[q2].y, sv0[q2].z, sv0[q2].w}; \
        float p1[4] = {sv1[q2].x, sv1[q2].y, sv1[q2].z, sv1[q2].w}; \
        _Pragma("unroll") for (int j = 0; j < 4; ++j) \
            *(unsigned*)&bw_[(n4 + j) * 8 + k8] = pk2(p0[j], p1[j]); } } while (0)

    f32x4 acc[2][4];
#pragma unroll
    for (int i = 0; i < 2; ++i)
#pragma unroll
        for (int f = 0; f < 4; ++f) acc[i][f] = {0.f,0.f,0.f,0.f};

    DN_LOAD(0);
    DN_WRITE(0);
    DN_ALOAD(0);

    for (int c = 0; c < DN_NC; ++c) {
        const int buf = c & 1;
        const bool pf = (c + 1 < DN_NC);
        __syncthreads();
        if (pf) DN_LOAD(c + 1);
#pragma unroll
        for (int s = 0; s < 4; ++s) {
            bf16x8 a0 = aR[s];
            bf16x8 a1 = aR[4 + s];
            if (pf) {
                const size_t ao_ = (size_t)((c + 1) * 16 + s * 4 + lg) * (S4 * 8);
                aR[s]     = *(const bf16x8*)(a0b + ao_);
                aR[4 + s] = *(const bf16x8*)(a1b + ao_);
            }
            const unsigned short* bf_ = &Bls[buf][((s * 4 + lg) * 64 + l16) * 8];
            bf16x8 b0 = *(const bf16x8*)(bf_);
            bf16x8 b1 = *(const bf16x8*)(bf_ + 128);
            bf16x8 b2 = *(const bf16x8*)(bf_ + 256);
            bf16x8 b3 = *(const bf16x8*)(bf_ + 384);
            acc[0][0] = MFMA16(a0, b0, acc[0][0]);
            acc[0][1] = MFMA16(a0, b1, acc[0][1]);
            acc[0][2] = MFMA16(a0, b2, acc[0][2]);
            acc[0][3] = MFMA16(a0, b3, acc[0][3]);
            acc[1][0] = MFMA16(a1, b0, acc[1][0]);
            acc[1][1] = MFMA16(a1, b1, acc[1][1]);
            acc[1][2] = MFMA16(a1, b2, acc[1][2]);
            acc[1][3] = MFMA16(a1, b3, acc[1][3]);
        }
        if (pf) DN_WRITE(buf ^ 1);
    }
#undef DN_ALOAD
#undef DN_LOAD
#undef DN_WRITE

#pragma unroll
    for (int i = 0; i < 2; ++i) {
        const int mloc = w * 32 + i * 16 + lg * 4;
#pragma unroll
        for (int r = 0; r < 4; ++r) {
            const int mrow = mt * 256 + mloc + r;
            if (mrow < count) {
                float* orow = ods + (size_t)(base + mrow) * H_DIM + nt * 64;
#pragma unroll
                for (int f = 0; f < 4; ++f)
                    orow[f * 16 + l16] = acc[i][f][r];
            }
        }
    }
}

// ---------------- combine: out[t] = sum of t's 4 slot rows ----------------
__global__ __launch_bounds__(256) void combine_kernel(
    const float* __restrict__ ods, const int* __restrict__ tok_slots,
    const int* __restrict__ slot_base, float* __restrict__ out)
{
    const int t = blockIdx.x;
    const int c0 = threadIdx.x * 8;
    const float* rows[TOPK];
#pragma unroll
    for (int r = 0; r < TOPK; ++r) {
        const int pk = tok_slots[t * TOPK + r];
        const int e = pk >> 12, pos = pk & 4095;
        rows[r] = ods + (size_t)(slot_base[e] + pos) * H_DIM + c0;
    }
    float4 a0 = {0.f,0.f,0.f,0.f}, a1 = {0.f,0.f,0.f,0.f};
#pragma unroll
    for (int r = 0; r < TOPK; ++r) {
        float4 v0 = *(const float4*)(rows[r]);
        float4 v1 = *(const float4*)(rows[r] + 4);
        a0.x += v0.x; a0.y += v0.y; a0.z += v0.z; a0.w += v0.w;
        a1.x += v1.x; a1.y += v1.y; a1.z += v1.z; a1.w += v1.w;
    }
    float* o = out + (size_t)t * H_DIM + c0;
    *(float4*)o = a0;
    *(float4*)(o + 4) = a1;
}

extern "C" void kernel_launch(void* const* d_in, const int* in_sizes, int n_in,
                              void* d_out, int out_size, void* d_ws, size_t ws_size,
                              hipStream_t stream) {
    const float* x      = (const float*)d_in[0];
    const float* gate_w = (const float*)d_in[1];
    const float* gup_w  = (const float*)d_in[2];
    const float* down_w = (const float*)d_in[3];
    float* out    = (float*)d_out;

    char* wsp = (char*)d_ws;
    int*   cnt       = (int*)(wsp);
    int*   slot_base = (int*)(wsp + 256);
    int*   tok_list  = (int*)(wsp + 4096);
    float* tok_w     = (float*)(wsp + 4096 + (size_t)E_NUM * T_TOK * 4);
    int*   tok_slots = (int*)(wsp + (768u << 10));

    size_t off = (size_t)1 << 20;
    unsigned short* xg_t = (unsigned short*)(wsp + off); off += (size_t)S4 * H_DIM * 2;  // 33.6MB
    unsigned short* h_t  = (unsigned short*)(wsp + off); off += (size_t)S4 * I_DIM * 2;  // 12.6MB
    float*          ods  = (float*)(wsp + off);          off += (size_t)S4 * H_DIM * 4;  // 67MB

    hipMemsetAsync(cnt, 0, 256, stream);

    router_kernel<<<T_TOK, 64, 0, stream>>>(x, gate_w, out + (size_t)T_TOK * H_DIM,
                                            cnt, tok_list, tok_w, tok_slots);
    scan_kernel<<<1, 64, 0, stream>>>(cnt, slot_base);
    gather_kernel<<<dim3(E_NUM, 256), 256, 0, stream>>>(x, cnt, slot_base, tok_list, xg_t);
    gateup_mfma<<<dim3(E_NUM, 24, 8), 512, 0, stream>>>(
        xg_t, gup_w, cnt, slot_base, tok_w, h_t);
    down_mfma<<<dim3(E_NUM, 32, 8), 512, 0, stream>>>(
        h_t, down_w, cnt, slot_base, ods);
    combine_kernel<<<T_TOK, 256, 0, stream>>>(ods, tok_slots, slot_base, out);
}

// Round 17
// 434.787 us; speedup vs baseline: 1.0193x; 1.0193x over previous
//
#include <hip/hip_runtime.h>
#include <hip/hip_bf16.h>

#define T_TOK 2048
#define H_DIM 2048
#define E_NUM 32
#define I_DIM 768
#define TOPK  4
#define S4    (T_TOK * TOPK)          // 8192 slots

typedef __attribute__((ext_vector_type(8))) short bf16x8;
typedef __attribute__((ext_vector_type(4))) float f32x4;

__device__ __forceinline__ unsigned pk2(float a, float b) {
    __hip_bfloat16 ha = __float2bfloat16(a);
    __hip_bfloat16 hb = __float2bfloat16(b);
    unsigned short ua = *(unsigned short*)&ha;
    unsigned short ub = *(unsigned short*)&hb;
    return (unsigned)ua | ((unsigned)ub << 16);
}

#define MFMA16(a, b, c) __builtin_amdgcn_mfma_f32_16x16x32_bf16(a, b, c, 0, 0, 0)

// ---------------- Router ----------------
__global__ __launch_bounds__(64) void router_kernel(
    const float* __restrict__ x, const float* __restrict__ gate_w,
    float* __restrict__ logits_out, int* __restrict__ cnt,
    int* __restrict__ tok_list, float* __restrict__ tok_w,
    int* __restrict__ tok_slots)
{
    const int t = blockIdx.x;
    const int lane = threadIdx.x;
    __shared__ float xs[H_DIM];
    const float4* __restrict__ xv = (const float4*)(x + (size_t)t * H_DIM);
    float4* xsv = (float4*)xs;
#pragma unroll
    for (int i = 0; i < H_DIM / 4 / 64; ++i) xsv[lane + i * 64] = xv[lane + i * 64];
    __syncthreads();

    const int e = lane & 31;
    const int half = lane >> 5;
    const float4* __restrict__ wv = (const float4*)(gate_w + (size_t)e * H_DIM) + half * (H_DIM / 8);
    const float4* __restrict__ xh = ((const float4*)xs) + half * (H_DIM / 8);
    float acc = 0.f;
#pragma unroll 4
    for (int i = 0; i < H_DIM / 8; ++i) {
        float4 w4 = wv[i], x4 = xh[i];
        acc += w4.x * x4.x + w4.y * x4.y + w4.z * x4.z + w4.w * x4.w;
    }
    acc += __shfl_xor(acc, 32, 64);
    if (lane < 32) logits_out[(size_t)t * E_NUM + e] = acc;

    float v = acc;
    float topv[TOPK]; int topi[TOPK];
#pragma unroll
    for (int r = 0; r < TOPK; ++r) {
        float bv = v; int bi = e;
#pragma unroll
        for (int off = 16; off >= 1; off >>= 1) {
            float ov = __shfl_xor(bv, off, 32);
            int   oi = __shfl_xor(bi, off, 32);
            if (ov > bv || (ov == bv && oi < bi)) { bv = ov; bi = oi; }
        }
        topv[r] = bv; topi[r] = bi;
        if (e == bi) v = -1e30f;
    }
    if (lane == 0) {
        float w[TOPK]; float s = 0.f;
#pragma unroll
        for (int r = 0; r < TOPK; ++r) { w[r] = expf(topv[r] - topv[0]); s += w[r]; }
        float inv = 1.f / s;
#pragma unroll
        for (int r = 0; r < TOPK; ++r) {
            int pos = atomicAdd(&cnt[topi[r]], 1);
            tok_list[topi[r] * T_TOK + pos] = t;
            tok_w  [topi[r] * T_TOK + pos] = w[r] * inv;
            tok_slots[t * TOPK + r] = (topi[r] << 12) | pos;
        }
    }
}

__global__ void scan_kernel(const int* __restrict__ cnt, int* __restrict__ slot_base)
{
    if (threadIdx.x == 0) {
        int s = 0;
        for (int e = 0; e < E_NUM; ++e) { slot_base[e] = s; s += cnt[e]; }
        slot_base[E_NUM] = s;
    }
}

// ------- Gather tokens per expert, convert x -> bf16 in K-PANEL layout -------
__global__ __launch_bounds__(256) void gather_kernel(
    const float* __restrict__ x, const int* __restrict__ cnt,
    const int* __restrict__ slot_base, const int* __restrict__ tok_list,
    unsigned short* __restrict__ xg_t)
{
    const int e = blockIdx.x;
    const int count = cnt[e];
    const int m0 = blockIdx.y * 8;
    if (m0 >= count) return;
    const int s8   = threadIdx.x >> 5;
    const int kc31 = threadIdx.x & 31;
    const int m = m0 + s8;
    if (m >= count) return;
    const int tok  = tok_list[e * T_TOK + m];
    const int slot = slot_base[e] + m;
    const float* __restrict__ src = x + (size_t)tok * H_DIM;
#pragma unroll
    for (int kcq = 0; kcq < 8; ++kcq) {
        const int kc = kcq * 32 + kc31;
        float4 a = *(const float4*)(src + kc * 8);
        float4 b = *(const float4*)(src + kc * 8 + 4);
        uint4 o;
        o.x = pk2(a.x, a.y); o.y = pk2(a.z, a.w);
        o.z = pk2(b.x, b.y); o.w = pk2(b.z, b.w);
        *(uint4*)(xg_t + ((size_t)kc * S4 + slot) * 8) = o;
    }
}

// ---------------- gate_up MFMA + silu + weight-scale -> h_t (panel bf16) -----
// tile 256(M) x (96 gate + 96 up), BK=64, 32 chunks; 8 strips/expert ->
// 256 working blocks = 1/CU, balanced; expert e's strips all on XCD e%8.
// Bytes/block: A 1MB + B 1.5MB (vs 1.5MB at BN=32 with 24 strips: total
// 2.7GB -> 1.9GB... total moved A 269MB + B 402MB).
#define GU_NC (H_DIM / 64)   // 32 chunks
__global__ __launch_bounds__(512, 2) void gateup_mfma(
    const unsigned short* __restrict__ xg_t, const float* __restrict__ gup_w,
    const int* __restrict__ cnt, const int* __restrict__ slot_base,
    const float* __restrict__ tok_w, unsigned short* __restrict__ h_t)
{
    const int e  = blockIdx.x;
    const int nt = blockIdx.y;       // 0..7, strip of 96 h-cols
    const int mt = blockIdx.z;
    const int count = cnt[e];
    if (mt * 256 >= count) return;
    const int tid  = threadIdx.x;
    const int lane = tid & 63;
    const int w    = tid >> 6;
    const int base = slot_base[e];
    const int l16  = lane & 15, lg = lane >> 4;

    __shared__ unsigned short Bls[2][2][4 * 192 * 8];  // [buf][sq][lg4][col192][8] 48KB
    __shared__ float wls[256];                         // 1KB

    if (tid < 256) {
        int m = mt * 256 + tid; if (m >= count) m = count - 1;
        wls[tid] = tok_w[e * T_TOK + m];
    }

    int m0 = mt * 256 + w * 32 + l16;      if (m0 >= count) m0 = count - 1;
    int m1 = mt * 256 + w * 32 + 16 + l16; if (m1 >= count) m1 = count - 1;
    const unsigned short* a0b = xg_t + (size_t)(base + m0) * 8;
    const unsigned short* a1b = xg_t + (size_t)(base + m1) * 8;

    // B staging: threads 0..255 gate, 256..511 up. Each: kb pair (32), 3 reps
    // of 4 cols (j*32 + n4), covering 96 cols.
    const int bhalf = tid >> 8;
    const int t8    = tid & 255;
    const int kb    = (t8 >> 3) * 2;     // 0,2,..,62 within BK=64
    const int n4    = (t8 & 7) * 4;      // 0..28
    const int sq    = kb >> 5;           // 0..1
    const int lgb   = (kb >> 3) & 3;     // 0..3
    const int k8    = kb & 7;
    const float* __restrict__ bbase =
        gup_w + ((size_t)e * H_DIM + kb) * (2 * I_DIM) + (size_t)bhalf * I_DIM + nt * 96 + n4;

    float4 sv0[3], sv1[3];
    bf16x8 aR[4];   // [s*2 + row]: chunk A granules

#define GU_ALOAD(C) do { _Pragma("unroll") for (int s = 0; s < 2; ++s) { \
        const size_t ao_ = (size_t)((C) * 8 + s * 4 + lg) * (S4 * 8); \
        aR[s]     = *(const bf16x8*)(a0b + ao_); \
        aR[2 + s] = *(const bf16x8*)(a1b + ao_); } } while (0)
#define GU_LOAD(C) do { _Pragma("unroll") for (int j = 0; j < 3; ++j) { \
        const float* s_ = bbase + (size_t)(C) * 64 * (2 * I_DIM) + j * 32; \
        sv0[j] = *(const float4*)s_; \
        sv1[j] = *(const float4*)(s_ + 2 * I_DIM); } } while (0)
#define GU_WRITE(BUF) do { _Pragma("unroll") for (int j = 0; j < 3; ++j) { \
        unsigned short* bw_ = &Bls[BUF][sq][(lgb * 192 + bhalf * 96 + j * 32 + n4) * 8 + k8]; \
        float p0[4] = {sv0[j].x, sv0[j].y, sv0[j].z, sv0[j].w}; \
        float p1[4] = {sv1[j].x, sv1[j].y, sv1[j].z, sv1[j].w}; \
        _Pragma("unroll") for (int q = 0; q < 4; ++q) \
            *(unsigned*)&bw_[q * 8] = pk2(p0[q], p1[q]); } } while (0)

    f32x4 accg[2][6], accu[2][6];
#pragma unroll
    for (int i = 0; i < 2; ++i)
#pragma unroll
        for (int f = 0; f < 6; ++f) { accg[i][f] = {0.f,0.f,0.f,0.f}; accu[i][f] = {0.f,0.f,0.f,0.f}; }

    GU_LOAD(0);
    GU_WRITE(0);

    for (int c = 0; c < GU_NC; ++c) {
        const int buf = c & 1;
        const bool pf = (c + 1 < GU_NC);
        __syncthreads();                 // Bls[buf] published for chunk c
        GU_ALOAD(c);                     // 4 concurrent A granule loads
        if (pf) GU_LOAD(c + 1);          // next-chunk B regs, issue-early
#pragma unroll
        for (int s = 0; s < 2; ++s) {
            bf16x8 a0 = aR[s];
            bf16x8 a1 = aR[2 + s];
            const unsigned short* bs_ = &Bls[buf][s][(lg * 192) * 8];
#pragma unroll
            for (int f = 0; f < 6; ++f) {
                bf16x8 bg = *(const bf16x8*)(bs_ + (f * 16 + l16) * 8);
                bf16x8 bu = *(const bf16x8*)(bs_ + (96 + f * 16 + l16) * 8);
                accg[0][f] = MFMA16(a0, bg, accg[0][f]);
                accg[1][f] = MFMA16(a1, bg, accg[1][f]);
                accu[0][f] = MFMA16(a0, bu, accu[0][f]);
                accu[1][f] = MFMA16(a1, bu, accu[1][f]);
            }
        }
        if (pf) GU_WRITE(buf ^ 1);       // write-late (loads landed under MFMAs)
    }
#undef GU_ALOAD
#undef GU_LOAD
#undef GU_WRITE

#pragma unroll
    for (int i = 0; i < 2; ++i) {
        const int mloc = w * 32 + i * 16 + lg * 4;
#pragma unroll
        for (int r = 0; r < 4; ++r) {
            const int mrow = mt * 256 + mloc + r;
            if (mrow < count) {
                const float wgt = wls[mloc + r];
                const size_t slot = (size_t)(base + mrow);
#pragma unroll
                for (int f = 0; f < 6; ++f) {
                    const int col = nt * 96 + f * 16 + l16;
                    float g = accg[i][f][r], u = accu[i][f][r];
                    float sv = g / (1.f + expf(-g));
                    __hip_bfloat16 hb = __float2bfloat16(wgt * u * sv);
                    h_t[((size_t)(col >> 3) * S4 + slot) * 8 + (col & 7)] = *(unsigned short*)&hb;
                }
            }
        }
    }
}

// ---------------- down MFMA -> slot-major f32 rows (no atomics) ----------------
// tile 256(M) x 256(N), BK=32, 24 chunks; 8 strips -> 256 working blocks.
#define DN_NC (I_DIM / 32)   // 24 chunks
__global__ __launch_bounds__(512, 2) void down_mfma(
    const unsigned short* __restrict__ h_t, const float* __restrict__ down_w,
    const int* __restrict__ cnt, const int* __restrict__ slot_base,
    float* __restrict__ ods)
{
    const int e  = blockIdx.x;
    const int nt = blockIdx.y;       // 0..7, strip of 256 out-cols
    const int mt = blockIdx.z;
    const int count = cnt[e];
    if (mt * 256 >= count) return;
    const int tid  = threadIdx.x;
    const int lane = tid & 63;
    const int w    = tid >> 6;
    const int base = slot_base[e];
    const int l16  = lane & 15, lg = lane >> 4;

    __shared__ unsigned short Bls[2][4 * 256 * 8];   // [buf][lg4][col256][8] 32KB

    int m0 = mt * 256 + w * 32 + l16;      if (m0 >= count) m0 = count - 1;
    int m1 = mt * 256 + w * 32 + 16 + l16; if (m1 >= count) m1 = count - 1;
    const unsigned short* a0b = h_t + (size_t)(base + m0) * 8;
    const unsigned short* a1b = h_t + (size_t)(base + m1) * 8;

    // B staging: kb pair (16), 2 reps of 4 cols (j*128 + n4) -> 256 cols.
    const int kb  = (tid >> 5) * 2;   // 0..30 within BK=32
    const int n4  = (tid & 31) * 4;   // 0..124
    const int lgb = kb >> 3;          // 0..3
    const int k8  = kb & 7;
    const float* __restrict__ bbase =
        down_w + ((size_t)e * I_DIM + kb) * H_DIM + nt * 256 + n4;

    float4 sv0[2], sv1[2];
    bf16x8 aR[2];

#define DN_ALOAD(C) do { \
        const size_t ao_ = (size_t)((C) * 4 + lg) * (S4 * 8); \
        aR[0] = *(const bf16x8*)(a0b + ao_); \
        aR[1] = *(const bf16x8*)(a1b + ao_); } while (0)
#define DN_LOAD(C) do { _Pragma("unroll") for (int j = 0; j < 2; ++j) { \
        const float* s_ = bbase + (size_t)(C) * 32 * H_DIM + j * 128; \
        sv0[j] = *(const float4*)s_; \
        sv1[j] = *(const float4*)(s_ + H_DIM); } } while (0)
#define DN_WRITE(BUF) do { _Pragma("unroll") for (int j = 0; j < 2; ++j) { \
        unsigned short* bw_ = &Bls[BUF][(lgb * 256 + j * 128 + n4) * 8 + k8]; \
        float p0[4] = {sv0[j].x, sv0[j].y, sv0[j].z, sv0[j].w}; \
        float p1[4] = {sv1[j].x, sv1[j].y, sv1[j].z, sv1[j].w}; \
        _Pragma("unroll") for (int q = 0; q < 4; ++q) \
            *(unsigned*)&bw_[q * 8] = pk2(p0[q], p1[q]); } } while (0)

    f32x4 acc[2][16];
#pragma unroll
    for (int i = 0; i < 2; ++i)
#pragma unroll
        for (int f = 0; f < 16; ++f) acc[i][f] = {0.f,0.f,0.f,0.f};

    DN_LOAD(0);
    DN_WRITE(0);

    for (int c = 0; c < DN_NC; ++c) {
        const int buf = c & 1;
        const bool pf = (c + 1 < DN_NC);
        __syncthreads();
        DN_ALOAD(c);
        if (pf) DN_LOAD(c + 1);
        {
            bf16x8 a0 = aR[0];
            bf16x8 a1 = aR[1];
            const unsigned short* bs_ = &Bls[buf][(lg * 256) * 8];
#pragma unroll
            for (int f = 0; f < 16; ++f) {
                bf16x8 b = *(const bf16x8*)(bs_ + (f * 16 + l16) * 8);
                acc[0][f] = MFMA16(a0, b, acc[0][f]);
                acc[1][f] = MFMA16(a1, b, acc[1][f]);
            }
        }
        if (pf) DN_WRITE(buf ^ 1);
    }
#undef DN_ALOAD
#undef DN_LOAD
#undef DN_WRITE

#pragma unroll
    for (int i = 0; i < 2; ++i) {
        const int mloc = w * 32 + i * 16 + lg * 4;
#pragma unroll
        for (int r = 0; r < 4; ++r) {
            const int mrow = mt * 256 + mloc + r;
            if (mrow < count) {
                float* orow = ods + (size_t)(base + mrow) * H_DIM + nt * 256;
#pragma unroll
                for (int f = 0; f < 16; ++f)
                    orow[f * 16 + l16] = acc[i][f][r];
            }
        }
    }
}

// ---------------- combine: out[t] = sum of t's 4 slot rows ----------------
__global__ __launch_bounds__(256) void combine_kernel(
    const float* __restrict__ ods, const int* __restrict__ tok_slots,
    const int* __restrict__ slot_base, float* __restrict__ out)
{
    const int t = blockIdx.x;
    const int c0 = threadIdx.x * 8;
    const float* rows[TOPK];
#pragma unroll
    for (int r = 0; r < TOPK; ++r) {
        const int pk = tok_slots[t * TOPK + r];
        const int e = pk >> 12, pos = pk & 4095;
        rows[r] = ods + (size_t)(slot_base[e] + pos) * H_DIM + c0;
    }
    float4 a0 = {0.f,0.f,0.f,0.f}, a1 = {0.f,0.f,0.f,0.f};
#pragma unroll
    for (int r = 0; r < TOPK; ++r) {
        float4 v0 = *(const float4*)(rows[r]);
        float4 v1 = *(const float4*)(rows[r] + 4);
        a0.x += v0.x; a0.y += v0.y; a0.z += v0.z; a0.w += v0.w;
        a1.x += v1.x; a1.y += v1.y; a1.z += v1.z; a1.w += v1.w;
    }
    float* o = out + (size_t)t * H_DIM + c0;
    *(float4*)o = a0;
    *(float4*)(o + 4) = a1;
}

extern "C" void kernel_launch(void* const* d_in, const int* in_sizes, int n_in,
                              void* d_out, int out_size, void* d_ws, size_t ws_size,
                              hipStream_t stream) {
    const float* x      = (const float*)d_in[0];
    const float* gate_w = (const float*)d_in[1];
    const float* gup_w  = (const float*)d_in[2];
    const float* down_w = (const float*)d_in[3];
    float* out    = (float*)d_out;

    char* wsp = (char*)d_ws;
    int*   cnt       = (int*)(wsp);
    int*   slot_base = (int*)(wsp + 256);
    int*   tok_list  = (int*)(wsp + 4096);
    float* tok_w     = (float*)(wsp + 4096 + (size_t)E_NUM * T_TOK * 4);
    int*   tok_slots = (int*)(wsp + (768u << 10));

    size_t off = (size_t)1 << 20;
    unsigned short* xg_t = (unsigned short*)(wsp + off); off += (size_t)S4 * H_DIM * 2;  // 33.6MB
    unsigned short* h_t  = (unsigned short*)(wsp + off); off += (size_t)S4 * I_DIM * 2;  // 12.6MB
    float*          ods  = (float*)(wsp + off);          off += (size_t)S4 * H_DIM * 4;  // 67MB

    hipMemsetAsync(cnt, 0, 256, stream);

    router_kernel<<<T_TOK, 64, 0, stream>>>(x, gate_w, out + (size_t)T_TOK * H_DIM,
                                            cnt, tok_list, tok_w, tok_slots);
    scan_kernel<<<1, 64, 0, stream>>>(cnt, slot_base);
    gather_kernel<<<dim3(E_NUM, 256), 256, 0, stream>>>(x, cnt, slot_base, tok_list, xg_t);
    gateup_mfma<<<dim3(E_NUM, 8, 8), 512, 0, stream>>>(
        xg_t, gup_w, cnt, slot_base, tok_w, h_t);
    down_mfma<<<dim3(E_NUM, 8, 8), 512, 0, stream>>>(
        h_t, down_w, cnt, slot_base, ods);
    combine_kernel<<<T_TOK, 256, 0, stream>>>(ods, tok_slots, slot_base, out);
}

// Round 18
// 421.406 us; speedup vs baseline: 1.0517x; 1.0318x over previous
//
#include <hip/hip_runtime.h>
#include <hip/hip_bf16.h>

#define T_TOK 2048
#define H_DIM 2048
#define E_NUM 32
#define I_DIM 768
#define TOPK  4
#define S4    (T_TOK * TOPK)          // 8192 slots

typedef __attribute__((ext_vector_type(8))) short bf16x8;
typedef __attribute__((ext_vector_type(4))) float f32x4;

__device__ __forceinline__ unsigned pk2(float a, float b) {
    __hip_bfloat16 ha = __float2bfloat16(a);
    __hip_bfloat16 hb = __float2bfloat16(b);
    unsigned short ua = *(unsigned short*)&ha;
    unsigned short ub = *(unsigned short*)&hb;
    return (unsigned)ua | ((unsigned)ub << 16);
}

__device__ __forceinline__ float bf2f(unsigned short u) {
    unsigned v = (unsigned)u << 16;
    return *(float*)&v;
}

#define MFMA16(a, b, c) __builtin_amdgcn_mfma_f32_16x16x32_bf16(a, b, c, 0, 0, 0)

// ---------------- Router ----------------
__global__ __launch_bounds__(64) void router_kernel(
    const float* __restrict__ x, const float* __restrict__ gate_w,
    float* __restrict__ logits_out, int* __restrict__ cnt,
    int* __restrict__ tok_list, float* __restrict__ tok_w,
    int* __restrict__ tok_slots)
{
    const int t = blockIdx.x;
    const int lane = threadIdx.x;
    __shared__ float xs[H_DIM];
    const float4* __restrict__ xv = (const float4*)(x + (size_t)t * H_DIM);
    float4* xsv = (float4*)xs;
#pragma unroll
    for (int i = 0; i < H_DIM / 4 / 64; ++i) xsv[lane + i * 64] = xv[lane + i * 64];
    __syncthreads();

    const int e = lane & 31;
    const int half = lane >> 5;
    const float4* __restrict__ wv = (const float4*)(gate_w + (size_t)e * H_DIM) + half * (H_DIM / 8);
    const float4* __restrict__ xh = ((const float4*)xs) + half * (H_DIM / 8);
    float acc = 0.f;
#pragma unroll 4
    for (int i = 0; i < H_DIM / 8; ++i) {
        float4 w4 = wv[i], x4 = xh[i];
        acc += w4.x * x4.x + w4.y * x4.y + w4.z * x4.z + w4.w * x4.w;
    }
    acc += __shfl_xor(acc, 32, 64);
    if (lane < 32) logits_out[(size_t)t * E_NUM + e] = acc;

    float v = acc;
    float topv[TOPK]; int topi[TOPK];
#pragma unroll
    for (int r = 0; r < TOPK; ++r) {
        float bv = v; int bi = e;
#pragma unroll
        for (int off = 16; off >= 1; off >>= 1) {
            float ov = __shfl_xor(bv, off, 32);
            int   oi = __shfl_xor(bi, off, 32);
            if (ov > bv || (ov == bv && oi < bi)) { bv = ov; bi = oi; }
        }
        topv[r] = bv; topi[r] = bi;
        if (e == bi) v = -1e30f;
    }
    if (lane == 0) {
        float w[TOPK]; float s = 0.f;
#pragma unroll
        for (int r = 0; r < TOPK; ++r) { w[r] = expf(topv[r] - topv[0]); s += w[r]; }
        float inv = 1.f / s;
#pragma unroll
        for (int r = 0; r < TOPK; ++r) {
            int pos = atomicAdd(&cnt[topi[r]], 1);
            tok_list[topi[r] * T_TOK + pos] = t;
            tok_w  [topi[r] * T_TOK + pos] = w[r] * inv;
            tok_slots[t * TOPK + r] = (topi[r] << 12) | pos;
        }
    }
}

__global__ void scan_kernel(const int* __restrict__ cnt, int* __restrict__ slot_base)
{
    if (threadIdx.x == 0) {
        int s = 0;
        for (int e = 0; e < E_NUM; ++e) { slot_base[e] = s; s += cnt[e]; }
        slot_base[E_NUM] = s;
    }
}

// ------- Gather tokens per expert, convert x -> bf16 in K-PANEL layout -------
__global__ __launch_bounds__(256) void gather_kernel(
    const float* __restrict__ x, const int* __restrict__ cnt,
    const int* __restrict__ slot_base, const int* __restrict__ tok_list,
    unsigned short* __restrict__ xg_t)
{
    const int e = blockIdx.x;
    const int count = cnt[e];
    const int m0 = blockIdx.y * 8;
    if (m0 >= count) return;
    const int s8   = threadIdx.x >> 5;
    const int kc31 = threadIdx.x & 31;
    const int m = m0 + s8;
    if (m >= count) return;
    const int tok  = tok_list[e * T_TOK + m];
    const int slot = slot_base[e] + m;
    const float* __restrict__ src = x + (size_t)tok * H_DIM;
#pragma unroll
    for (int kcq = 0; kcq < 8; ++kcq) {
        const int kc = kcq * 32 + kc31;
        float4 a = *(const float4*)(src + kc * 8);
        float4 b = *(const float4*)(src + kc * 8 + 4);
        uint4 o;
        o.x = pk2(a.x, a.y); o.y = pk2(a.z, a.w);
        o.z = pk2(b.x, b.y); o.w = pk2(b.z, b.w);
        *(uint4*)(xg_t + ((size_t)kc * S4 + slot) * 8) = o;
    }
}

// ---------------- gate_up MFMA + silu + weight-scale -> h_t (panel bf16) -----
// tile 256(M) x (96 gate + 96 up), BK=64, 32 chunks; row-padded B LDS
// (193 granules/row -> +4 bank shift/row) kills the 8-way write conflict.
#define GU_NC (H_DIM / 64)   // 32 chunks
#define GU_RS (193 * 8)      // padded row stride in shorts
__global__ __launch_bounds__(512, 2) void gateup_mfma(
    const unsigned short* __restrict__ xg_t, const float* __restrict__ gup_w,
    const int* __restrict__ cnt, const int* __restrict__ slot_base,
    const float* __restrict__ tok_w, unsigned short* __restrict__ h_t)
{
    const int e  = blockIdx.x;
    const int nt = blockIdx.y;       // 0..7, strip of 96 h-cols
    const int mt = blockIdx.z;
    const int count = cnt[e];
    if (mt * 256 >= count) return;
    const int tid  = threadIdx.x;
    const int lane = tid & 63;
    const int w    = tid >> 6;
    const int base = slot_base[e];
    const int l16  = lane & 15, lg = lane >> 4;

    __shared__ unsigned short Bls[2][2][4 * GU_RS];    // 48.25KB
    __shared__ float wls[256];                         // 1KB

    if (tid < 256) {
        int m = mt * 256 + tid; if (m >= count) m = count - 1;
        wls[tid] = tok_w[e * T_TOK + m];
    }

    int m0 = mt * 256 + w * 32 + l16;      if (m0 >= count) m0 = count - 1;
    int m1 = mt * 256 + w * 32 + 16 + l16; if (m1 >= count) m1 = count - 1;
    const unsigned short* a0b = xg_t + (size_t)(base + m0) * 8;
    const unsigned short* a1b = xg_t + (size_t)(base + m1) * 8;

    const int bhalf = tid >> 8;
    const int t8    = tid & 255;
    const int kb    = (t8 >> 3) * 2;     // 0,2,..,62 within BK=64
    const int n4    = (t8 & 7) * 4;      // 0..28
    const int sq    = kb >> 5;           // 0..1
    const int lgb   = (kb >> 3) & 3;     // 0..3
    const int k8    = kb & 7;
    const float* __restrict__ bbase =
        gup_w + ((size_t)e * H_DIM + kb) * (2 * I_DIM) + (size_t)bhalf * I_DIM + nt * 96 + n4;

    float4 sv0[3], sv1[3];
    bf16x8 aR[4];

#define GU_ALOAD(C) do { _Pragma("unroll") for (int s = 0; s < 2; ++s) { \
        const size_t ao_ = (size_t)((C) * 8 + s * 4 + lg) * (S4 * 8); \
        aR[s]     = *(const bf16x8*)(a0b + ao_); \
        aR[2 + s] = *(const bf16x8*)(a1b + ao_); } } while (0)
#define GU_LOAD(C) do { _Pragma("unroll") for (int j = 0; j < 3; ++j) { \
        const float* s_ = bbase + (size_t)(C) * 64 * (2 * I_DIM) + j * 32; \
        sv0[j] = *(const float4*)s_; \
        sv1[j] = *(const float4*)(s_ + 2 * I_DIM); } } while (0)
#define GU_WRITE(BUF) do { _Pragma("unroll") for (int j = 0; j < 3; ++j) { \
        unsigned short* bw_ = &Bls[BUF][sq][lgb * GU_RS + (bhalf * 96 + j * 32 + n4) * 8 + k8]; \
        float p0[4] = {sv0[j].x, sv0[j].y, sv0[j].z, sv0[j].w}; \
        float p1[4] = {sv1[j].x, sv1[j].y, sv1[j].z, sv1[j].w}; \
        _Pragma("unroll") for (int q = 0; q < 4; ++q) \
            *(unsigned*)&bw_[q * 8] = pk2(p0[q], p1[q]); } } while (0)

    f32x4 accg[2][6], accu[2][6];
#pragma unroll
    for (int i = 0; i < 2; ++i)
#pragma unroll
        for (int f = 0; f < 6; ++f) { accg[i][f] = {0.f,0.f,0.f,0.f}; accu[i][f] = {0.f,0.f,0.f,0.f}; }

    GU_LOAD(0);
    GU_WRITE(0);

    for (int c = 0; c < GU_NC; ++c) {
        const int buf = c & 1;
        const bool pf = (c + 1 < GU_NC);
        __syncthreads();
        GU_ALOAD(c);
        if (pf) GU_LOAD(c + 1);
#pragma unroll
        for (int s = 0; s < 2; ++s) {
            bf16x8 a0 = aR[s];
            bf16x8 a1 = aR[2 + s];
            const unsigned short* bs_ = &Bls[buf][s][lg * GU_RS];
#pragma unroll
            for (int f = 0; f < 6; ++f) {
                bf16x8 bg = *(const bf16x8*)(bs_ + (f * 16 + l16) * 8);
                bf16x8 bu = *(const bf16x8*)(bs_ + (96 + f * 16 + l16) * 8);
                accg[0][f] = MFMA16(a0, bg, accg[0][f]);
                accg[1][f] = MFMA16(a1, bg, accg[1][f]);
                accu[0][f] = MFMA16(a0, bu, accu[0][f]);
                accu[1][f] = MFMA16(a1, bu, accu[1][f]);
            }
        }
        if (pf) GU_WRITE(buf ^ 1);
    }
#undef GU_ALOAD
#undef GU_LOAD
#undef GU_WRITE

#pragma unroll
    for (int i = 0; i < 2; ++i) {
        const int mloc = w * 32 + i * 16 + lg * 4;
#pragma unroll
        for (int r = 0; r < 4; ++r) {
            const int mrow = mt * 256 + mloc + r;
            if (mrow < count) {
                const float wgt = wls[mloc + r];
                const size_t slot = (size_t)(base + mrow);
#pragma unroll
                for (int f = 0; f < 6; ++f) {
                    const int col = nt * 96 + f * 16 + l16;
                    float g = accg[i][f][r], u = accu[i][f][r];
                    float sv = g / (1.f + expf(-g));
                    __hip_bfloat16 hb = __float2bfloat16(wgt * u * sv);
                    h_t[((size_t)(col >> 3) * S4 + slot) * 8 + (col & 7)] = *(unsigned short*)&hb;
                }
            }
        }
    }
}

// ---------------- down MFMA -> slot-major BF16 rows (no atomics) ----------------
// tile 256(M) x 256(N), BK=32, 24 chunks; 8 strips -> 256 working blocks.
#define DN_NC (I_DIM / 32)   // 24 chunks
__global__ __launch_bounds__(512, 2) void down_mfma(
    const unsigned short* __restrict__ h_t, const float* __restrict__ down_w,
    const int* __restrict__ cnt, const int* __restrict__ slot_base,
    unsigned short* __restrict__ ods)
{
    const int e  = blockIdx.x;
    const int nt = blockIdx.y;       // 0..7, strip of 256 out-cols
    const int mt = blockIdx.z;
    const int count = cnt[e];
    if (mt * 256 >= count) return;
    const int tid  = threadIdx.x;
    const int lane = tid & 63;
    const int w    = tid >> 6;
    const int base = slot_base[e];
    const int l16  = lane & 15, lg = lane >> 4;

    __shared__ unsigned short Bls[2][4 * 256 * 8];   // [buf][lg4][col256][8] 32KB

    int m0 = mt * 256 + w * 32 + l16;      if (m0 >= count) m0 = count - 1;
    int m1 = mt * 256 + w * 32 + 16 + l16; if (m1 >= count) m1 = count - 1;
    const unsigned short* a0b = h_t + (size_t)(base + m0) * 8;
    const unsigned short* a1b = h_t + (size_t)(base + m1) * 8;

    const int kb  = (tid >> 5) * 2;   // 0..30 within BK=32
    const int n4  = (tid & 31) * 4;   // 0..124
    const int lgb = kb >> 3;          // 0..3
    const int k8  = kb & 7;
    const float* __restrict__ bbase =
        down_w + ((size_t)e * I_DIM + kb) * H_DIM + nt * 256 + n4;

    float4 sv0[2], sv1[2];
    bf16x8 aR[2];

#define DN_ALOAD(C) do { \
        const size_t ao_ = (size_t)((C) * 4 + lg) * (S4 * 8); \
        aR[0] = *(const bf16x8*)(a0b + ao_); \
        aR[1] = *(const bf16x8*)(a1b + ao_); } while (0)
#define DN_LOAD(C) do { _Pragma("unroll") for (int j = 0; j < 2; ++j) { \
        const float* s_ = bbase + (size_t)(C) * 32 * H_DIM + j * 128; \
        sv0[j] = *(const float4*)s_; \
        sv1[j] = *(const float4*)(s_ + H_DIM); } } while (0)
#define DN_WRITE(BUF) do { _Pragma("unroll") for (int j = 0; j < 2; ++j) { \
        unsigned short* bw_ = &Bls[BUF][(lgb * 256 + j * 128 + n4) * 8 + k8]; \
        float p0[4] = {sv0[j].x, sv0[j].y, sv0[j].z, sv0[j].w}; \
        float p1[4] = {sv1[j].x, sv1[j].y, sv1[j].z, sv1[j].w}; \
        _Pragma("unroll") for (int q = 0; q < 4; ++q) \
            *(unsigned*)&bw_[q * 8] = pk2(p0[q], p1[q]); } } while (0)

    f32x4 acc[2][16];
#pragma unroll
    for (int i = 0; i < 2; ++i)
#pragma unroll
        for (int f = 0; f < 16; ++f) acc[i][f] = {0.f,0.f,0.f,0.f};

    DN_LOAD(0);
    DN_WRITE(0);

    for (int c = 0; c < DN_NC; ++c) {
        const int buf = c & 1;
        const bool pf = (c + 1 < DN_NC);
        __syncthreads();
        DN_ALOAD(c);
        if (pf) DN_LOAD(c + 1);
        {
            bf16x8 a0 = aR[0];
            bf16x8 a1 = aR[1];
            const unsigned short* bs_ = &Bls[buf][(lg * 256) * 8];
#pragma unroll
            for (int f = 0; f < 16; ++f) {
                bf16x8 b = *(const bf16x8*)(bs_ + (f * 16 + l16) * 8);
                acc[0][f] = MFMA16(a0, b, acc[0][f]);
                acc[1][f] = MFMA16(a1, b, acc[1][f]);
            }
        }
        if (pf) DN_WRITE(buf ^ 1);
    }
#undef DN_ALOAD
#undef DN_LOAD
#undef DN_WRITE

#pragma unroll
    for (int i = 0; i < 2; ++i) {
        const int mloc = w * 32 + i * 16 + lg * 4;
#pragma unroll
        for (int r = 0; r < 4; ++r) {
            const int mrow = mt * 256 + mloc + r;
            if (mrow < count) {
                unsigned short* orow = ods + (size_t)(base + mrow) * H_DIM + nt * 256;
#pragma unroll
                for (int f = 0; f < 16; ++f) {
                    __hip_bfloat16 hb = __float2bfloat16(acc[i][f][r]);
                    orow[f * 16 + l16] = *(unsigned short*)&hb;
                }
            }
        }
    }
}

// ---------------- combine: out[t] = sum of t's 4 bf16 slot rows ----------------
__global__ __launch_bounds__(256) void combine_kernel(
    const unsigned short* __restrict__ ods, const int* __restrict__ tok_slots,
    const int* __restrict__ slot_base, float* __restrict__ out)
{
    const int t = blockIdx.x;
    const int c0 = threadIdx.x * 8;
    const unsigned short* rows[TOPK];
#pragma unroll
    for (int r = 0; r < TOPK; ++r) {
        const int pk = tok_slots[t * TOPK + r];
        const int e = pk >> 12, pos = pk & 4095;
        rows[r] = ods + (size_t)(slot_base[e] + pos) * H_DIM + c0;
    }
    float s[8] = {0.f, 0.f, 0.f, 0.f, 0.f, 0.f, 0.f, 0.f};
#pragma unroll
    for (int r = 0; r < TOPK; ++r) {
        uint4 v = *(const uint4*)(rows[r]);
        const unsigned short* u = (const unsigned short*)&v;
#pragma unroll
        for (int k = 0; k < 8; ++k) s[k] += bf2f(u[k]);
    }
    float* o = out + (size_t)t * H_DIM + c0;
    float4 o0 = {s[0], s[1], s[2], s[3]};
    float4 o1 = {s[4], s[5], s[6], s[7]};
    *(float4*)o = o0;
    *(float4*)(o + 4) = o1;
}

extern "C" void kernel_launch(void* const* d_in, const int* in_sizes, int n_in,
                              void* d_out, int out_size, void* d_ws, size_t ws_size,
                              hipStream_t stream) {
    const float* x      = (const float*)d_in[0];
    const float* gate_w = (const float*)d_in[1];
    const float* gup_w  = (const float*)d_in[2];
    const float* down_w = (const float*)d_in[3];
    float* out    = (float*)d_out;

    char* wsp = (char*)d_ws;
    int*   cnt       = (int*)(wsp);
    int*   slot_base = (int*)(wsp + 256);
    int*   tok_list  = (int*)(wsp + 4096);
    float* tok_w     = (float*)(wsp + 4096 + (size_t)E_NUM * T_TOK * 4);
    int*   tok_slots = (int*)(wsp + (768u << 10));

    size_t off = (size_t)1 << 20;
    unsigned short* xg_t = (unsigned short*)(wsp + off); off += (size_t)S4 * H_DIM * 2;  // 33.6MB
    unsigned short* h_t  = (unsigned short*)(wsp + off); off += (size_t)S4 * I_DIM * 2;  // 12.6MB
    unsigned short* ods  = (unsigned short*)(wsp + off); off += (size_t)S4 * H_DIM * 2;  // 33.6MB

    hipMemsetAsync(cnt, 0, 256, stream);

    router_kernel<<<T_TOK, 64, 0, stream>>>(x, gate_w, out + (size_t)T_TOK * H_DIM,
                                            cnt, tok_list, tok_w, tok_slots);
    scan_kernel<<<1, 64, 0, stream>>>(cnt, slot_base);
    gather_kernel<<<dim3(E_NUM, 256), 256, 0, stream>>>(x, cnt, slot_base, tok_list, xg_t);
    gateup_mfma<<<dim3(E_NUM, 8, 8), 512, 0, stream>>>(
        xg_t, gup_w, cnt, slot_base, tok_w, h_t);
    down_mfma<<<dim3(E_NUM, 8, 8), 512, 0, stream>>>(
        h_t, down_w, cnt, slot_base, ods);
    combine_kernel<<<T_TOK, 256, 0, stream>>>(ods, tok_slots, slot_base, out);
}